// Round 15
// baseline (474.769 us; speedup 1.0000x reference)
//
#include <hip/hip_runtime.h>

constexpr int BB = 2, HH = 16, LL = 2048, DD = 128;
constexpr int QB = 64, KB = 32, NKT = LL / KB;   // 64 k-tiles
constexpr float SCALE = 0.08838834764831845f;    // 1/sqrt(128)

typedef __attribute__((ext_vector_type(8))) short bf16x8;
typedef __attribute__((ext_vector_type(8))) unsigned short u16x8;
typedef __attribute__((ext_vector_type(4))) float f32x4;
typedef __attribute__((ext_vector_type(16))) float f32x16;
typedef __attribute__((ext_vector_type(4))) int i32x4;

static __device__ __forceinline__ unsigned short f2bf(float f) {
  unsigned int u = __builtin_bit_cast(unsigned int, f);
  u += 0x7fffu + ((u >> 16) & 1u);   // RNE
  return (unsigned short)(u >> 16);
}
static __device__ __forceinline__ float bf2f(unsigned short h) {
  return __builtin_bit_cast(float, (unsigned int)h << 16);
}

#define GLD16(gsrc, ldst) __builtin_amdgcn_global_load_lds( \
    (const __attribute__((address_space(1))) void*)(gsrc), \
    (__attribute__((address_space(3))) void*)(ldst), 16, 0, 0)

// ---------------- prep ----------------
//   kbT tile [16 dslots][32 keys][8 d] (bf16)   (serves 32x32 A-frags: dslot=m*2+hi)
//   vtT tile [4 kc][128 d][8 keys]     (bf16)   (serves 32x32 B-frags: kc=kb/8+hi)
//   biasW[tile=b*2048+qt*64+kt][wave][lane][16] bf16, entry r -> key (r&3)+8*(r>>2)+4*hi
__global__ __launch_bounds__(256)
void prep_kernel(const float* __restrict__ k, const float* __restrict__ v,
                 const int* __restrict__ mask, const float* __restrict__ probs,
                 const float* __restrict__ alphap,
                 unsigned short* __restrict__ kbT, unsigned short* __restrict__ vtT,
                 unsigned short* __restrict__ biasW)
{
  __shared__ unsigned short sT[128 * 40];   // V^T tile, 80 B rows
  const int bid = blockIdx.x;
  const int bh = bid >> 6, kt = bid & 63;
  const int t = threadIdx.x;
  const float alpha = alphap[0];
  const size_t tileBase = (size_t)bid * 4096;   // bid == bh*64 + kt
  const float* kg = k + ((size_t)bh * LL + kt * 32) * DD;
  const float* vg = v + ((size_t)bh * LL + kt * 32) * DD;

  // K -> 16B-block-transposed tile
  #pragma unroll
  for (int s = t; s < 512; s += 256) {
    int dsl = s >> 5, key = s & 31;
    const float* src = kg + key * DD + dsl * 8;
    float4 a = *(const float4*)src;
    float4 c = *(const float4*)(src + 4);
    u16x8 w;
    w[0] = f2bf(a.x); w[1] = f2bf(a.y); w[2] = f2bf(a.z); w[3] = f2bf(a.w);
    w[4] = f2bf(c.x); w[5] = f2bf(c.y); w[6] = f2bf(c.z); w[7] = f2bf(c.w);
    *(u16x8*)(kbT + tileBase + (size_t)s * 8) = w;
  }
  // V -> sT (transpose)
  #pragma unroll
  for (int i = 0; i < 4; ++i) {
    int idx = i * 256 + t;
    int key = idx >> 5, d4 = (idx & 31) * 4;
    float4 x = ((const float4*)vg)[idx];
    sT[(d4 + 0) * 40 + key] = f2bf(x.x);
    sT[(d4 + 1) * 40 + key] = f2bf(x.y);
    sT[(d4 + 2) * 40 + key] = f2bf(x.z);
    sT[(d4 + 3) * 40 + key] = f2bf(x.w);
  }
  // biasW: 2 tiles per block, packed in 32x32 D-register order
  #pragma unroll
  for (int it = 0; it < 2; ++it) {
    int ti = bid * 2 + it;               // 0..4095
    int b = ti >> 11;
    int tq = (ti >> 6) & 31;
    int tk = ti & 63;
    int wv = t >> 7;                     // 0..1
    int ln = (t >> 1) & 63;              // 0..63
    int rh = t & 1;                      // 0..1 (regs 0-7 / 8-15)
    int l31 = ln & 31, hi = ln >> 5;
    int qrow = tq * 64 + wv * 32 + l31;
    int kbase = tk * 32 + 4 * hi + rh * 16;
    const float* pr = probs + (size_t)b * LL * LL + (size_t)qrow * LL + kbase;
    const int* mr = mask + (size_t)b * LL * LL + (size_t)qrow * LL + kbase;
    float4 f0 = *(const float4*)(pr);
    float4 f1 = *(const float4*)(pr + 8);
    int4 m0 = *(const int4*)(mr);
    int4 m1 = *(const int4*)(mr + 8);
    u16x8 o;
    o[0] = f2bf(m0.x ? f0.x * alpha : -1e30f);
    o[1] = f2bf(m0.y ? f0.y * alpha : -1e30f);
    o[2] = f2bf(m0.z ? f0.z * alpha : -1e30f);
    o[3] = f2bf(m0.w ? f0.w * alpha : -1e30f);
    o[4] = f2bf(m1.x ? f1.x * alpha : -1e30f);
    o[5] = f2bf(m1.y ? f1.y * alpha : -1e30f);
    o[6] = f2bf(m1.z ? f1.z * alpha : -1e30f);
    o[7] = f2bf(m1.w ? f1.w * alpha : -1e30f);
    *(u16x8*)(biasW + (size_t)ti * 2048 + wv * 1024 + ln * 16 + rh * 8) = o;
  }
  __syncthreads();
  // sT -> vtT tile [kc][d][8]
  #pragma unroll
  for (int s = t; s < 512; s += 256) {
    int kc = s >> 7, d = s & 127;
    u16x8 w = *(const u16x8*)&sT[d * 40 + kc * 8];
    *(u16x8*)(vtT + tileBase + (size_t)s * 8) = w;
  }
}

#define ZERO16 {0.f,0.f,0.f,0.f,0.f,0.f,0.f,0.f,0.f,0.f,0.f,0.f,0.f,0.f,0.f,0.f}

// common per-kernel prologue pieces (32x32 structure, WG = 128 = 2 waves)
#define COMMON_DECODE \
  const int tid = threadIdx.x; \
  const int lane = tid & 63; \
  const int wid = tid >> 6; \
  const int l31 = lane & 31; \
  const int hi5 = lane >> 5; \
  const int bid = blockIdx.x; \
  const int work = ((bid & 7) << 7) | (bid >> 3); \
  const int bh = work >> 5; \
  const int qt = work & 31; \
  const int b = bh >> 4; \
  const int q0 = qt * QB; \
  const int qrow = q0 + wid * 32 + l31;

// Q B-frags: lane holds Q[q=l31][d = m*16 + hi5*8 + j]
#define LOAD_QFRAGS \
  bf16x8 qf0, qf1, qf2, qf3, qf4, qf5, qf6, qf7; \
  { \
    const float* qs = q + (size_t)(bh * LL + qrow) * DD + hi5 * 8; \
    _Pragma("unroll") \
    for (int m = 0; m < 8; ++m) { \
      float4 a = *(const float4*)(qs + m * 16); \
      float4 c = *(const float4*)(qs + m * 16 + 4); \
      u16x8 w; \
      w[0]=f2bf(a.x); w[1]=f2bf(a.y); w[2]=f2bf(a.z); w[3]=f2bf(a.w); \
      w[4]=f2bf(c.x); w[5]=f2bf(c.y); w[6]=f2bf(c.z); w[7]=f2bf(c.w); \
      bf16x8 f = __builtin_bit_cast(bf16x8, w); \
      switch (m) { case 0: qf0=f; break; case 1: qf1=f; break; \
                   case 2: qf2=f; break; case 3: qf3=f; break; \
                   case 4: qf4=f; break; case 5: qf5=f; break; \
                   case 6: qf6=f; break; default: qf7=f; } \
    } \
  }

// 8KB tile staged by 128 threads: 4 issues x (128 lanes x 16B)
#define DMA_T(ARR, BASE, KT) do { \
  _Pragma("unroll") \
  for (int i_ = 0; i_ < 4; ++i_) \
    GLD16((BASE) + (size_t)(KT) * 4096 + (i_ * 128 + tid) * 8, \
          &ARR[i_ * 1024 + (tid >> 6) * 512]); } while (0)

// QK 32x32x16: A = K (dslot = m*2+hi5), B = Q frag m ; D[key][q=l31]
#define QK32(SBUF) \
  f32x16 s = ZERO16; \
  { \
    bf16x8 kf; \
    kf = *(const bf16x8*)&SBUF[(( 0 + hi5) * 32 + l31) * 8]; \
    s = __builtin_amdgcn_mfma_f32_32x32x16_bf16(kf, qf0, s, 0, 0, 0); \
    kf = *(const bf16x8*)&SBUF[(( 2 + hi5) * 32 + l31) * 8]; \
    s = __builtin_amdgcn_mfma_f32_32x32x16_bf16(kf, qf1, s, 0, 0, 0); \
    kf = *(const bf16x8*)&SBUF[(( 4 + hi5) * 32 + l31) * 8]; \
    s = __builtin_amdgcn_mfma_f32_32x32x16_bf16(kf, qf2, s, 0, 0, 0); \
    kf = *(const bf16x8*)&SBUF[(( 6 + hi5) * 32 + l31) * 8]; \
    s = __builtin_amdgcn_mfma_f32_32x32x16_bf16(kf, qf3, s, 0, 0, 0); \
    kf = *(const bf16x8*)&SBUF[(( 8 + hi5) * 32 + l31) * 8]; \
    s = __builtin_amdgcn_mfma_f32_32x32x16_bf16(kf, qf4, s, 0, 0, 0); \
    kf = *(const bf16x8*)&SBUF[((10 + hi5) * 32 + l31) * 8]; \
    s = __builtin_amdgcn_mfma_f32_32x32x16_bf16(kf, qf5, s, 0, 0, 0); \
    kf = *(const bf16x8*)&SBUF[((12 + hi5) * 32 + l31) * 8]; \
    s = __builtin_amdgcn_mfma_f32_32x32x16_bf16(kf, qf6, s, 0, 0, 0); \
    kf = *(const bf16x8*)&SBUF[((14 + hi5) * 32 + l31) * 8]; \
    s = __builtin_amdgcn_mfma_f32_32x32x16_bf16(kf, qf7, s, 0, 0, 0); \
  }

// ---------------- pass A: rowsums -> invW ----------------
__global__ __launch_bounds__(128, 4)
void passA_kernel(const float* __restrict__ q, const unsigned short* __restrict__ kbT,
                  const unsigned short* __restrict__ biasW, float* __restrict__ invW)
{
  __shared__ unsigned short sK[2][4096];
  COMMON_DECODE
  const unsigned short* kbh = kbT + (size_t)bh * 64 * 4096;
  const unsigned short* bg = biasW + ((size_t)(b * 32 + qt) * 64) * 2048 + wid * 1024 + lane * 16;
  LOAD_QFRAGS

  DMA_T(sK[0], kbh, 0);
  u16x8 cb0 = *(const u16x8*)(bg);
  u16x8 cb1 = *(const u16x8*)(bg + 8);
  float sum = 0.f;
  for (int kt = 0; kt < NKT; ++kt) {
    const int cur = kt & 1;
    __syncthreads();
    if (kt + 1 < NKT) DMA_T(sK[cur ^ 1], kbh, kt + 1);
    u16x8 b0 = cb0, b1 = cb1;
    if (kt + 1 < NKT) {
      cb0 = *(const u16x8*)(bg + (size_t)(kt + 1) * 2048);
      cb1 = *(const u16x8*)(bg + (size_t)(kt + 1) * 2048 + 8);
    }
    QK32(sK[cur])
    #pragma unroll
    for (int r = 0; r < 8; ++r) sum += __expf(s[r] * SCALE + bf2f(b0[r]));
    #pragma unroll
    for (int r = 0; r < 8; ++r) sum += __expf(s[r + 8] * SCALE + bf2f(b1[r]));
  }
  sum += __shfl_xor(sum, 32, 64);   // lanes l and l+32 hold same q, disjoint keys
  if (lane < 32)
    invW[(size_t)bh * LL + qrow] = 1.0f / sum;
}

// ---------------- pass B: attn_p + O ----------------
__global__ __launch_bounds__(128, 3)
void passB_kernel(const float* __restrict__ q, const unsigned short* __restrict__ kbT,
                  const unsigned short* __restrict__ vtT, const unsigned short* __restrict__ biasW,
                  const float* __restrict__ invW,
                  float* __restrict__ outA, float* __restrict__ outP)
{
  __shared__ unsigned short sK[2][4096];
  __shared__ unsigned short sVt[2][4096];
  COMMON_DECODE
  const unsigned short* kbh = kbT + (size_t)bh * 64 * 4096;
  const unsigned short* vbh = vtT + (size_t)bh * 64 * 4096;
  const unsigned short* bg = biasW + ((size_t)(b * 32 + qt) * 64) * 2048 + wid * 1024 + lane * 16;
  float* oA = outA + (size_t)(bh * LL + q0) * DD;
  float* oPr = outP + (size_t)bh * LL * LL + (size_t)qrow * LL;
  const float inv = invW[(size_t)bh * LL + qrow];
  LOAD_QFRAGS

  f32x16 acc0 = ZERO16, acc1 = ZERO16, acc2 = ZERO16, acc3 = ZERO16;
  u16x8 cb0, cb1;

  #define BBODY(KT) do { \
    const int cur = (KT) & 1; \
    u16x8 b0 = cb0, b1 = cb1; \
    if ((KT) + 1 < NKT) { \
      cb0 = *(const u16x8*)(bg + (size_t)((KT) + 1) * 2048); \
      cb1 = *(const u16x8*)(bg + (size_t)((KT) + 1) * 2048 + 8); \
    } \
    QK32(sK[cur]) \
    f32x16 p; \
    _Pragma("unroll") \
    for (int r = 0; r < 8; ++r) p[r] = __expf(s[r] * SCALE + bf2f(b0[r])) * inv; \
    _Pragma("unroll") \
    for (int r = 0; r < 8; ++r) p[r + 8] = __expf(s[r + 8] * SCALE + bf2f(b1[r])) * inv; \
    /* attn_p: 4 x float4 nt-stores; reg quad r4 -> keys base {0,8,16,24}+4*hi5 */ \
    { \
      f32x4 st; \
      st[0]=p[0];  st[1]=p[1];  st[2]=p[2];  st[3]=p[3]; \
      __builtin_nontemporal_store(st, (f32x4*)(oPr + (KT) * 32 + 4 * hi5)); \
      st[0]=p[4];  st[1]=p[5];  st[2]=p[6];  st[3]=p[7]; \
      __builtin_nontemporal_store(st, (f32x4*)(oPr + (KT) * 32 + 8 + 4 * hi5)); \
      st[0]=p[8];  st[1]=p[9];  st[2]=p[10]; st[3]=p[11]; \
      __builtin_nontemporal_store(st, (f32x4*)(oPr + (KT) * 32 + 16 + 4 * hi5)); \
      st[0]=p[12]; st[1]=p[13]; st[2]=p[14]; st[3]=p[15]; \
      __builtin_nontemporal_store(st, (f32x4*)(oPr + (KT) * 32 + 24 + 4 * hi5)); \
    } \
    /* P -> PV A-frags: cvt_pk pairs, cross-half shfl, select */ \
    unsigned D0,D1,D2,D3,D4,D5,D6,D7; \
    asm("v_cvt_pk_bf16_f32 %0, %1, %2" : "=v"(D0) : "v"(p[0]),  "v"(p[1])); \
    asm("v_cvt_pk_bf16_f32 %0, %1, %2" : "=v"(D1) : "v"(p[2]),  "v"(p[3])); \
    asm("v_cvt_pk_bf16_f32 %0, %1, %2" : "=v"(D2) : "v"(p[4]),  "v"(p[5])); \
    asm("v_cvt_pk_bf16_f32 %0, %1, %2" : "=v"(D3) : "v"(p[6]),  "v"(p[7])); \
    asm("v_cvt_pk_bf16_f32 %0, %1, %2" : "=v"(D4) : "v"(p[8]),  "v"(p[9])); \
    asm("v_cvt_pk_bf16_f32 %0, %1, %2" : "=v"(D5) : "v"(p[10]), "v"(p[11])); \
    asm("v_cvt_pk_bf16_f32 %0, %1, %2" : "=v"(D6) : "v"(p[12]), "v"(p[13])); \
    asm("v_cvt_pk_bf16_f32 %0, %1, %2" : "=v"(D7) : "v"(p[14]), "v"(p[15])); \
    int X0 = __shfl_xor((int)D0, 32, 64), X1 = __shfl_xor((int)D1, 32, 64); \
    int X2 = __shfl_xor((int)D2, 32, 64), X3 = __shfl_xor((int)D3, 32, 64); \
    int X4 = __shfl_xor((int)D4, 32, 64), X5 = __shfl_xor((int)D5, 32, 64); \
    int X6 = __shfl_xor((int)D6, 32, 64), X7 = __shfl_xor((int)D7, 32, 64); \
    const bool lo = (hi5 == 0); \
    i32x4 w0, w1; \
    w0[0] = lo ? (int)D0 : X2;  w0[1] = lo ? (int)D1 : X3; \
    w0[2] = lo ? X0 : (int)D2;  w0[3] = lo ? X1 : (int)D3; \
    w1[0] = lo ? (int)D4 : X6;  w1[1] = lo ? (int)D5 : X7; \
    w1[2] = lo ? X4 : (int)D6;  w1[3] = lo ? X5 : (int)D7; \
    bf16x8 aP0 = __builtin_bit_cast(bf16x8, w0); \
    bf16x8 aP1 = __builtin_bit_cast(bf16x8, w1); \
    /* PV: per 32-d chunk, 2 MFMAs (k=0-15, 16-31) */ \
    bf16x8 bV; \
    bV = *(const bf16x8*)&sVt[cur][((0 + hi5) * 128 +  0 + l31) * 8]; \
    acc0 = __builtin_amdgcn_mfma_f32_32x32x16_bf16(aP0, bV, acc0, 0, 0, 0); \
    bV = *(const bf16x8*)&sVt[cur][((2 + hi5) * 128 +  0 + l31) * 8]; \
    acc0 = __builtin_amdgcn_mfma_f32_32x32x16_bf16(aP1, bV, acc0, 0, 0, 0); \
    bV = *(const bf16x8*)&sVt[cur][((0 + hi5) * 128 + 32 + l31) * 8]; \
    acc1 = __builtin_amdgcn_mfma_f32_32x32x16_bf16(aP0, bV, acc1, 0, 0, 0); \
    bV = *(const bf16x8*)&sVt[cur][((2 + hi5) * 128 + 32 + l31) * 8]; \
    acc1 = __builtin_amdgcn_mfma_f32_32x32x16_bf16(aP1, bV, acc1, 0, 0, 0); \
    bV = *(const bf16x8*)&sVt[cur][((0 + hi5) * 128 + 64 + l31) * 8]; \
    acc2 = __builtin_amdgcn_mfma_f32_32x32x16_bf16(aP0, bV, acc2, 0, 0, 0); \
    bV = *(const bf16x8*)&sVt[cur][((2 + hi5) * 128 + 64 + l31) * 8]; \
    acc2 = __builtin_amdgcn_mfma_f32_32x32x16_bf16(aP1, bV, acc2, 0, 0, 0); \
    bV = *(const bf16x8*)&sVt[cur][((0 + hi5) * 128 + 96 + l31) * 8]; \
    acc3 = __builtin_amdgcn_mfma_f32_32x32x16_bf16(aP0, bV, acc3, 0, 0, 0); \
    bV = *(const bf16x8*)&sVt[cur][((2 + hi5) * 128 + 96 + l31) * 8]; \
    acc3 = __builtin_amdgcn_mfma_f32_32x32x16_bf16(aP1, bV, acc3, 0, 0, 0); \
  } while (0)

  // prologue
  cb0 = *(const u16x8*)(bg);
  cb1 = *(const u16x8*)(bg + 8);
  DMA_T(sK[0], kbh, 0); DMA_T(sVt[0], vbh, 0);
  asm volatile("s_waitcnt vmcnt(0)\n\ts_barrier" ::: "memory");
  DMA_T(sK[1], kbh, 1); DMA_T(sVt[1], vbh, 1);
  BBODY(0);
  for (int kt = 1; kt < NKT; ++kt) {
    // counted: allow the 4 newest (this lane's nt-stores) to stay in flight
    asm volatile("s_waitcnt vmcnt(4)\n\ts_barrier" ::: "memory");
    if (kt + 1 < NKT) {
      const int c2 = (kt + 1) & 1;
      DMA_T(sK[c2], kbh, kt + 1); DMA_T(sVt[c2], vbh, kt + 1);
    }
    BBODY(kt);
  }

  // ---- store attention: lane holds O[q=(r&3)+8*(r>>2)+4*hi5][d=dc*32+l31] ----
  #define STA(ACC, DC) \
    _Pragma("unroll") \
    for (int r = 0; r < 16; ++r) { \
      int qr = (r & 3) + 8 * (r >> 2) + 4 * hi5; \
      __builtin_nontemporal_store(ACC[r], \
          oA + (size_t)(wid * 32 + qr) * DD + (DC) * 32 + l31); \
    }
  STA(acc0, 0) STA(acc1, 1) STA(acc2, 2) STA(acc3, 3)
  #undef STA
}

extern "C" void kernel_launch(void* const* d_in, const int* in_sizes, int n_in,
                              void* d_out, int out_size, void* d_ws, size_t ws_size,
                              hipStream_t stream) {
  const float* q = (const float*)d_in[0];
  const float* k = (const float*)d_in[1];
  const float* v = (const float*)d_in[2];
  const int* mask = (const int*)d_in[3];
  const float* probs = (const float*)d_in[4];
  const float* alpha = (const float*)d_in[5];
  float* outA = (float*)d_out;
  float* outP = outA + (size_t)BB * HH * LL * DD;
  unsigned short* kbT = (unsigned short*)d_ws;
  unsigned short* vtT = kbT + (size_t)32 * 64 * 4096;
  unsigned short* biasW = vtT + (size_t)32 * 64 * 4096;
  float* invW = (float*)(biasW + (size_t)4096 * 2048);
  hipLaunchKernelGGL(prep_kernel, dim3(32 * 64), dim3(256), 0, stream,
                     k, v, mask, probs, alpha, kbT, vtT, biasW);
  hipLaunchKernelGGL(passA_kernel, dim3(BB * HH * (LL / QB)), dim3(128), 0, stream,
                     q, kbT, biasW, invW);
  hipLaunchKernelGGL(passB_kernel, dim3(BB * HH * (LL / QB)), dim3(128), 0, stream,
                     q, kbT, vtT, biasW, invW, outA, outP);
}

// Round 16
// 257.070 us; speedup vs baseline: 1.8468x; 1.8468x over previous
//
#include <hip/hip_runtime.h>

constexpr int BB = 2, HH = 16, LL = 2048, DD = 128;
constexpr int QB = 64, KB = 32, NKT = LL / KB;   // 64 k-tiles
constexpr float SCALE = 0.08838834764831845f;    // 1/sqrt(128)

typedef __attribute__((ext_vector_type(8))) short bf16x8;
typedef __attribute__((ext_vector_type(8))) unsigned short u16x8;
typedef __attribute__((ext_vector_type(4))) float f32x4;
typedef __attribute__((ext_vector_type(4))) int i32x4;

static __device__ __forceinline__ unsigned short f2bf(float f) {
  unsigned int u = __builtin_bit_cast(unsigned int, f);
  u += 0x7fffu + ((u >> 16) & 1u);   // RNE
  return (unsigned short)(u >> 16);
}
static __device__ __forceinline__ float bf2f(unsigned short h) {
  return __builtin_bit_cast(float, (unsigned int)h << 16);
}

#define GLD16(gsrc, ldst) __builtin_amdgcn_global_load_lds( \
    (const __attribute__((address_space(1))) void*)(gsrc), \
    (__attribute__((address_space(3))) void*)(ldst), 16, 0, 0)

// ---------------- prep ----------------
//   kbT tile [16 dslots][32 keys][8 d] (bf16)
//   vtT tile [4 kc][128 d][8 keys]     (bf16)
//   biasT[b][qt][kt][wid][lane][8]     (bf16) lane-packed: wave's per-iter bias
//     = ONE coalesced u16x8/lane; entry j<4 -> key l4*4+j, j>=4 -> 16+l4*4+j-4
__global__ __launch_bounds__(256)
void prep_kernel(const float* __restrict__ k, const float* __restrict__ v,
                 const int* __restrict__ mask, const float* __restrict__ probs,
                 const float* __restrict__ alphap,
                 unsigned short* __restrict__ kbT, unsigned short* __restrict__ vtT,
                 unsigned short* __restrict__ biasW)
{
  __shared__ unsigned short sT[128 * 40];   // V^T tile, 80 B rows
  const int bid = blockIdx.x;
  const int bh = bid >> 6, kt = bid & 63;
  const int t = threadIdx.x;
  const float alpha = alphap[0];
  const size_t tileBase = (size_t)bid * 4096;   // bid == bh*64 + kt
  const float* kg = k + ((size_t)bh * LL + kt * 32) * DD;
  const float* vg = v + ((size_t)bh * LL + kt * 32) * DD;

  // K -> 16B-block-transposed tile
  #pragma unroll
  for (int s = t; s < 512; s += 256) {
    int dsl = s >> 5, key = s & 31;
    const float* src = kg + key * DD + dsl * 8;
    float4 a = *(const float4*)src;
    float4 c = *(const float4*)(src + 4);
    u16x8 w;
    w[0] = f2bf(a.x); w[1] = f2bf(a.y); w[2] = f2bf(a.z); w[3] = f2bf(a.w);
    w[4] = f2bf(c.x); w[5] = f2bf(c.y); w[6] = f2bf(c.z); w[7] = f2bf(c.w);
    *(u16x8*)(kbT + tileBase + (size_t)s * 8) = w;
  }
  // V -> sT (transpose)
  #pragma unroll
  for (int i = 0; i < 4; ++i) {
    int idx = i * 256 + t;
    int key = idx >> 5, d4 = (idx & 31) * 4;
    float4 x = ((const float4*)vg)[idx];
    sT[(d4 + 0) * 40 + key] = f2bf(x.x);
    sT[(d4 + 1) * 40 + key] = f2bf(x.y);
    sT[(d4 + 2) * 40 + key] = f2bf(x.z);
    sT[(d4 + 3) * 40 + key] = f2bf(x.w);
  }
  // biasT: 2 tiles per block (4096 tiles total, 2048 u16 each)
  #pragma unroll
  for (int it = 0; it < 2; ++it) {
    int tileIdx = bid * 2 + it;            // 0..4095
    int b = tileIdx >> 11;
    int rem = tileIdx & 2047;
    int tq = rem >> 6;                     // qt 0..31
    int tk = rem & 63;                     // kt 0..63
    int row = ((t >> 6) << 4) + (t & 15);  // widx*16 + l15
    int kc = ((t >> 4) & 3) * 4;           // l4*4
    const float* pr = probs + (size_t)b * LL * LL + (size_t)(tq * 64 + row) * LL + tk * 32;
    const int* mr = mask + (size_t)b * LL * LL + (size_t)(tq * 64 + row) * LL + tk * 32;
    float4 f0 = *(const float4*)(pr + kc);
    float4 f1 = *(const float4*)(pr + kc + 16);
    int4 m0 = *(const int4*)(mr + kc);
    int4 m1 = *(const int4*)(mr + kc + 16);
    u16x8 o;
    o[0] = f2bf(m0.x ? f0.x * alpha : -1e30f);
    o[1] = f2bf(m0.y ? f0.y * alpha : -1e30f);
    o[2] = f2bf(m0.z ? f0.z * alpha : -1e30f);
    o[3] = f2bf(m0.w ? f0.w * alpha : -1e30f);
    o[4] = f2bf(m1.x ? f1.x * alpha : -1e30f);
    o[5] = f2bf(m1.y ? f1.y * alpha : -1e30f);
    o[6] = f2bf(m1.z ? f1.z * alpha : -1e30f);
    o[7] = f2bf(m1.w ? f1.w * alpha : -1e30f);
    *(u16x8*)(biasW + (size_t)tileIdx * 2048 + t * 8) = o;
  }
  __syncthreads();
  // sT -> vtT tile [kc][d][8]
  #pragma unroll
  for (int s = t; s < 512; s += 256) {
    int kc = s >> 7, d = s & 127;
    u16x8 w = *(const u16x8*)&sT[d * 40 + kc * 8];
    *(u16x8*)(vtT + tileBase + (size_t)s * 8) = w;
  }
}

// ---------------- pass A: rowsums -> invW ----------------
__global__ __launch_bounds__(256, 6)
void passA_kernel(const float* __restrict__ q, const unsigned short* __restrict__ kbT,
                  const unsigned short* __restrict__ biasW, float* __restrict__ invW)
{
  __shared__ unsigned short sK[2][4096];

  const int tid = threadIdx.x;
  const int lane = tid & 63;
  const int wid = tid >> 6;
  const int l15 = lane & 15;
  const int l4 = lane >> 4;

  const int bid = blockIdx.x;
  const int work = ((bid & 7) << 7) | (bid >> 3);
  const int bh = work >> 5;
  const int qt = work & 31;
  const int b = bh >> 4;
  const int q0 = qt * QB;
  const int row16 = wid << 4;

  const unsigned short* kbh = kbT + (size_t)bh * 64 * 4096;
  const unsigned short* bg = biasW + ((size_t)(b * 32 + qt) * 64) * 2048 + (wid << 9) + (lane << 3);

  bf16x8 qf0, qf1, qf2, qf3;
  {
    const float* qs = q + (size_t)(bh * LL + q0 + row16 + l15) * DD + l4 * 8;
    #define LQ(FR, KC) { \
      float4 a = *(const float4*)(qs + (KC) * 32); \
      float4 c = *(const float4*)(qs + (KC) * 32 + 4); \
      FR[0]=(short)f2bf(a.x); FR[1]=(short)f2bf(a.y); FR[2]=(short)f2bf(a.z); FR[3]=(short)f2bf(a.w); \
      FR[4]=(short)f2bf(c.x); FR[5]=(short)f2bf(c.y); FR[6]=(short)f2bf(c.z); FR[7]=(short)f2bf(c.w); }
    LQ(qf0, 0) LQ(qf1, 1) LQ(qf2, 2) LQ(qf3, 3)
    #undef LQ
  }

  #define DMA_K(BUF, KT) do { \
    GLD16(kbh + (size_t)(KT) * 4096 + tid * 8,         &sK[BUF][wid << 9]); \
    GLD16(kbh + (size_t)(KT) * 4096 + (256 + tid) * 8, &sK[BUF][2048 + (wid << 9)]); } while (0)

  #define QKS(KC, QF) { \
    bf16x8 k0 = *(const bf16x8*)&sK[cur][(((KC) * 4 + l4) * 32 + l15) * 8]; \
    a0 = __builtin_amdgcn_mfma_f32_16x16x32_bf16(k0, QF, a0, 0, 0, 0); \
    bf16x8 k1 = *(const bf16x8*)&sK[cur][(((KC) * 4 + l4) * 32 + 16 + l15) * 8]; \
    a1 = __builtin_amdgcn_mfma_f32_16x16x32_bf16(k1, QF, a1, 0, 0, 0); }

  DMA_K(0, 0);
  u16x8 cnb = *(const u16x8*)(bg);
  float sum = 0.f;
  for (int kt = 0; kt < NKT; ++kt) {
    const int cur = kt & 1;
    __syncthreads();
    if (kt + 1 < NKT) DMA_K(cur ^ 1, kt + 1);
    u16x8 bt = cnb;
    if (kt + 1 < NKT) cnb = *(const u16x8*)(bg + (size_t)(kt + 1) * 2048);
    f32x4 a0 = {0.f,0.f,0.f,0.f}, a1 = {0.f,0.f,0.f,0.f};
    QKS(0, qf0) QKS(1, qf1) QKS(2, qf2) QKS(3, qf3)
    sum += __expf(a0[0] * SCALE + bf2f(bt[0]));
    sum += __expf(a0[1] * SCALE + bf2f(bt[1]));
    sum += __expf(a0[2] * SCALE + bf2f(bt[2]));
    sum += __expf(a0[3] * SCALE + bf2f(bt[3]));
    sum += __expf(a1[0] * SCALE + bf2f(bt[4]));
    sum += __expf(a1[1] * SCALE + bf2f(bt[5]));
    sum += __expf(a1[2] * SCALE + bf2f(bt[6]));
    sum += __expf(a1[3] * SCALE + bf2f(bt[7]));
  }
  sum += __shfl_xor(sum, 16, 64);
  sum += __shfl_xor(sum, 32, 64);
  if (l4 == 0)
    invW[(size_t)bh * LL + q0 + row16 + l15] = 1.0f / sum;
  #undef DMA_K
  #undef QKS
}

// ---------------- pass B: attn_p + O ----------------
__global__ __launch_bounds__(256, 4)
void passB_kernel(const float* __restrict__ q, const unsigned short* __restrict__ kbT,
                  const unsigned short* __restrict__ vtT, const unsigned short* __restrict__ biasW,
                  const float* __restrict__ invW,
                  float* __restrict__ outA, float* __restrict__ outP)
{
  __shared__ unsigned short sK[2][4096];
  __shared__ unsigned short sVt[2][4096];

  const int tid = threadIdx.x;
  const int lane = tid & 63;
  const int wid = tid >> 6;
  const int l15 = lane & 15;
  const int l4 = lane >> 4;

  const int bid = blockIdx.x;
  const int work = ((bid & 7) << 7) | (bid >> 3);
  const int bh = work >> 5;
  const int qt = work & 31;
  const int b = bh >> 4;
  const int q0 = qt * QB;
  const int row16 = wid << 4;

  const unsigned short* kbh = kbT + (size_t)bh * 64 * 4096;
  const unsigned short* vbh = vtT + (size_t)bh * 64 * 4096;
  const unsigned short* bg = biasW + ((size_t)(b * 32 + qt) * 64) * 2048 + (wid << 9) + (lane << 3);
  float* oA = outA + (size_t)(bh * LL + q0) * DD;
  float* oPr = outP + (size_t)bh * LL * LL + (size_t)(q0 + row16 + l15) * LL;

  const float inv = invW[(size_t)bh * LL + q0 + row16 + l15];

  bf16x8 qf0, qf1, qf2, qf3;
  {
    const float* qs = q + (size_t)(bh * LL + q0 + row16 + l15) * DD + l4 * 8;
    #define LQ(FR, KC) { \
      float4 a = *(const float4*)(qs + (KC) * 32); \
      float4 c = *(const float4*)(qs + (KC) * 32 + 4); \
      FR[0]=(short)f2bf(a.x); FR[1]=(short)f2bf(a.y); FR[2]=(short)f2bf(a.z); FR[3]=(short)f2bf(a.w); \
      FR[4]=(short)f2bf(c.x); FR[5]=(short)f2bf(c.y); FR[6]=(short)f2bf(c.z); FR[7]=(short)f2bf(c.w); }
    LQ(qf0, 0) LQ(qf1, 1) LQ(qf2, 2) LQ(qf3, 3)
    #undef LQ
  }

  #define DMA_K(BUF, KT) do { \
    GLD16(kbh + (size_t)(KT) * 4096 + tid * 8,         &sK[BUF][wid << 9]); \
    GLD16(kbh + (size_t)(KT) * 4096 + (256 + tid) * 8, &sK[BUF][2048 + (wid << 9)]); } while (0)
  #define DMA_V(BUF, KT) do { \
    GLD16(vbh + (size_t)(KT) * 4096 + tid * 8,         &sVt[BUF][wid << 9]); \
    GLD16(vbh + (size_t)(KT) * 4096 + (256 + tid) * 8, &sVt[BUF][2048 + (wid << 9)]); } while (0)

  #define QKS(KC, QF) { \
    bf16x8 k0 = *(const bf16x8*)&sK[cur][(((KC) * 4 + l4) * 32 + l15) * 8]; \
    a0 = __builtin_amdgcn_mfma_f32_16x16x32_bf16(k0, QF, a0, 0, 0, 0); \
    bf16x8 k1 = *(const bf16x8*)&sK[cur][(((KC) * 4 + l4) * 32 + 16 + l15) * 8]; \
    a1 = __builtin_amdgcn_mfma_f32_16x16x32_bf16(k1, QF, a1, 0, 0, 0); }

  const int srcA = l15 + (((l4 << 1) + 0) & 3) * 16;
  const int srcB = l15 + (((l4 << 1) + 1) & 3) * 16;
  const bool hiTile = (l4 >= 2);

  f32x4 oacc[8];
  #pragma unroll
  for (int dt = 0; dt < 8; ++dt) oacc[dt] = (f32x4){0.f,0.f,0.f,0.f};

  u16x8 cnb;

  // body macro: compute iteration KT from buf cur; prefetches handled by caller
  #define BBODY(KT) do { \
    const int cur = (KT) & 1; \
    u16x8 bt = cnb; \
    if ((KT) + 1 < NKT) cnb = *(const u16x8*)(bg + (size_t)((KT) + 1) * 2048); \
    f32x4 a0 = {0.f,0.f,0.f,0.f}, a1 = {0.f,0.f,0.f,0.f}; \
    QKS(0, qf0) QKS(1, qf1) QKS(2, qf2) QKS(3, qf3) \
    f32x4 p0, p1; \
    p0[0] = __expf(a0[0] * SCALE + bf2f(bt[0])) * inv; \
    p0[1] = __expf(a0[1] * SCALE + bf2f(bt[1])) * inv; \
    p0[2] = __expf(a0[2] * SCALE + bf2f(bt[2])) * inv; \
    p0[3] = __expf(a0[3] * SCALE + bf2f(bt[3])) * inv; \
    p1[0] = __expf(a1[0] * SCALE + bf2f(bt[4])) * inv; \
    p1[1] = __expf(a1[1] * SCALE + bf2f(bt[5])) * inv; \
    p1[2] = __expf(a1[2] * SCALE + bf2f(bt[6])) * inv; \
    p1[3] = __expf(a1[3] * SCALE + bf2f(bt[7])) * inv; \
    __builtin_nontemporal_store(p0, (f32x4*)(oPr + (KT) * 32 + (l4 << 2))); \
    __builtin_nontemporal_store(p1, (f32x4*)(oPr + (KT) * 32 + 16 + (l4 << 2))); \
    unsigned d00, d01, d10, d11; \
    asm("v_cvt_pk_bf16_f32 %0, %1, %2" : "=v"(d00) : "v"(p0[0]), "v"(p0[1])); \
    asm("v_cvt_pk_bf16_f32 %0, %1, %2" : "=v"(d01) : "v"(p0[2]), "v"(p0[3])); \
    asm("v_cvt_pk_bf16_f32 %0, %1, %2" : "=v"(d10) : "v"(p1[0]), "v"(p1[1])); \
    asm("v_cvt_pk_bf16_f32 %0, %1, %2" : "=v"(d11) : "v"(p1[2]), "v"(p1[3])); \
    int a00 = __shfl((int)d00, srcA, 64); \
    int a01 = __shfl((int)d01, srcA, 64); \
    int a02 = __shfl((int)d00, srcB, 64); \
    int a03 = __shfl((int)d01, srcB, 64); \
    int b00 = __shfl((int)d10, srcA, 64); \
    int b01 = __shfl((int)d11, srcA, 64); \
    int b02 = __shfl((int)d10, srcB, 64); \
    int b03 = __shfl((int)d11, srcB, 64); \
    i32x4 fw; \
    fw[0] = hiTile ? b00 : a00; \
    fw[1] = hiTile ? b01 : a01; \
    fw[2] = hiTile ? b02 : a02; \
    fw[3] = hiTile ? b03 : a03; \
    bf16x8 aP = __builtin_bit_cast(bf16x8, fw); \
    _Pragma("unroll") \
    for (int dt = 0; dt < 8; ++dt) { \
      bf16x8 bV = *(const bf16x8*)&sVt[cur][(l4 * 128 + dt * 16 + l15) * 8]; \
      oacc[dt] = __builtin_amdgcn_mfma_f32_16x16x32_bf16(aP, bV, oacc[dt], 0, 0, 0); \
    } \
  } while (0)

  // prologue: bias first, then DMA (stores later stay the newest-2 ops)
  cnb = *(const u16x8*)(bg);
  DMA_K(0, 0); DMA_V(0, 0);
  asm volatile("s_waitcnt vmcnt(0)\n\ts_barrier" ::: "memory");
  // iter 0 (no stores outstanding yet, but uniform handling after this)
  DMA_K(1, 1); DMA_V(1, 1);
  BBODY(0);
  for (int kt = 1; kt < NKT; ++kt) {
    // counted wait: all-but-2 (the two nt-stores) complete -> DMA(kt)+bias done,
    // stores keep draining in background
    asm volatile("s_waitcnt vmcnt(2)\n\ts_barrier" ::: "memory");
    if (kt + 1 < NKT) {
      const int c2 = (kt + 1) & 1;
      DMA_K(c2, kt + 1); DMA_V(c2, kt + 1);
    }
    BBODY(kt);
  }

  #pragma unroll
  for (int dt = 0; dt < 8; ++dt) {
    #pragma unroll
    for (int r = 0; r < 4; ++r) {
      __builtin_nontemporal_store(oacc[dt][r],
          oA + (size_t)(row16 + (l4 << 2) + r) * DD + dt * 16 + l15);
    }
  }
}

extern "C" void kernel_launch(void* const* d_in, const int* in_sizes, int n_in,
                              void* d_out, int out_size, void* d_ws, size_t ws_size,
                              hipStream_t stream) {
  const float* q = (const float*)d_in[0];
  const float* k = (const float*)d_in[1];
  const float* v = (const float*)d_in[2];
  const int* mask = (const int*)d_in[3];
  const float* probs = (const float*)d_in[4];
  const float* alpha = (const float*)d_in[5];
  float* outA = (float*)d_out;
  float* outP = outA + (size_t)BB * HH * LL * DD;
  unsigned short* kbT = (unsigned short*)d_ws;
  unsigned short* vtT = kbT + (size_t)32 * 64 * 4096;
  unsigned short* biasW = vtT + (size_t)32 * 64 * 4096;
  float* invW = (float*)(biasW + (size_t)4096 * 2048);
  hipLaunchKernelGGL(prep_kernel, dim3(32 * 64), dim3(256), 0, stream,
                     k, v, mask, probs, alpha, kbT, vtT, biasW);
  hipLaunchKernelGGL(passA_kernel, dim3(BB * HH * (LL / QB)), dim3(256), 0, stream,
                     q, kbT, biasW, invW);
  hipLaunchKernelGGL(passB_kernel, dim3(BB * HH * (LL / QB)), dim3(256), 0, stream,
                     q, kbT, vtT, biasW, invW, outA, outP);
}